// Round 3
// baseline (44543.890 us; speedup 1.0000x reference)
//
#include <hip/hip_runtime.h>
#include <hip/hip_bf16.h>

// TrueMarkovChain v3: same decomposition as v2 (A:64 / B:64 / C:32 / X:96 WGs,
// LDS-staged weights, PF=16 prefetch ring). Sync rework: ALL cross-WG shared
// data (z1/z2/sbf/xc, flags) uses volatile accesses (sc0=sc1=1 on gfx950:
// loads bypass L1/L2 -> read L3 coherent point; stores write through).
// No __threadfence / no __hip_atomic => no buffer_wbl2 / buffer_inv cache
// nukes. Release = __syncthreads (vmcnt drain) + volatile flag store.
// Acquire = volatile poll + __syncthreads.

typedef __bf16 v8bf __attribute__((ext_vector_type(8)));
typedef float f32x4 __attribute__((ext_vector_type(4)));

__device__ inline f32x4 mfma16(v8bf a, v8bf b, f32x4 c) {
  return __builtin_amdgcn_mfma_f32_16x16x32_bf16(a, b, c, 0, 0, 0);
}
__device__ inline float silu_f(float x) { return x / (1.f + __expf(-x)); }

__device__ inline v8bf cvt8(float4 a, float4 b) {
  v8bf v;
  v[0] = (__bf16)a.x; v[1] = (__bf16)a.y; v[2] = (__bf16)a.z; v[3] = (__bf16)a.w;
  v[4] = (__bf16)b.x; v[5] = (__bf16)b.y; v[6] = (__bf16)b.z; v[7] = (__bf16)b.w;
  return v;
}

// Coherent (L2-bypassing) accessors: volatile => sc0=1 sc1=1 on gfx950.
__device__ inline v8bf vld8(const __bf16* p) {
  union { f32x4 f; v8bf b; } u;
  u.f = *(const volatile f32x4*)p;  // single global_load_dwordx4 sc0 sc1
  return u.b;
}
__device__ inline float vldbf(const __bf16* p) {
  return (float)*(const volatile __bf16*)p;
}
__device__ inline void vstbf(__bf16* p, float v) {
  *(volatile __bf16*)p = (__bf16)v;
}

// ---------------- fp32 -> bf16 strided converter (8 elems/thread) ------------
__global__ void cvt_kernel(const float* __restrict__ src, __bf16* __restrict__ dst,
                           int total8, int log2cols, int sstride, int soff) {
  int i = blockIdx.x * 256 + threadIdx.x;
  if (i >= total8) return;
  long long e = (long long)i * 8;
  int r = (int)(e >> log2cols);
  int c = (int)(e & ((1LL << log2cols) - 1));
  const float* s = src + (size_t)r * sstride + soff + c;
  float4 f0 = *(const float4*)(s);
  float4 f1 = *(const float4*)(s + 4);
  *(v8bf*)(dst + e) = cvt8(f0, f1);
}

// ---------------- sync primitives (fence-free, coherent accesses) ------------
__device__ inline void flag_set(unsigned* f, unsigned v) {
  asm volatile("s_waitcnt vmcnt(0)" ::: "memory");  // this wave's stores done
  __syncthreads();  // all waves drained (compiler emits vmcnt(0) before barrier)
  if (threadIdx.x == 0) *(volatile unsigned*)f = v;
}
__device__ inline void flags_wait(const unsigned* f, int n, unsigned target) {
  if (threadIdx.x < 64) {
    const volatile unsigned* p = f + (threadIdx.x < n ? (int)threadIdx.x : 0);
    while (*p < target) __builtin_amdgcn_s_sleep(1);
  }
  __syncthreads();
}
// A waits: fC[0..31] >= t  AND  fX[t] >= 1
__device__ inline void wait_A(const unsigned* fC, const unsigned* fXt, unsigned t) {
  if (threadIdx.x < 64) {
    const int lane = threadIdx.x;
    const volatile unsigned* p = (lane < 32) ? (fC + lane) : fXt;
    const unsigned tgt = (lane < 32) ? t : 1u;
    while (*p < tgt) __builtin_amdgcn_s_sleep(1);
  }
  __syncthreads();
}

// ---------------- weight staging into LDS [K/8][NR][8] -----------------------
template <int K, int NR>
__device__ inline void stage_w(const __bf16* __restrict__ wg, __bf16* wl, int tid) {
  constexpr int TOT = (K / 8) * NR;
#pragma unroll
  for (int idx = tid; idx < TOT; idx += 256) {
    const int kb = idx / NR, n = idx % NR;
    *(v8bf*)(wl + (size_t)idx * 8) = *(const v8bf*)(wg + (size_t)n * K + kb * 8);
  }
}

// ---------------- LDS-weight GEMM, PF-deep coherent activation prefetch -----
template <int KITERS, int NF, int PF>
__device__ inline void lds_gemm(const __bf16* act, int ldk, const __bf16* wl,
                                int lane, f32x4 (&acc)[2][NF]) {
  const int lr = lane & 15, lc = lane >> 4;
  const __bf16* a0 = act + (size_t)lr * ldk + lc * 8;
  const __bf16* a1 = a0 + (size_t)16 * ldk;
  const __bf16* bl = wl + lr * 8;
  v8bf ab0[PF], ab1[PF];
#pragma unroll
  for (int i = 0; i < PF; ++i) {
    ab0[i] = vld8(a0 + i * 32);
    ab1[i] = vld8(a1 + i * 32);
  }
#pragma unroll
  for (int it = 0; it < KITERS; ++it) {
    v8bf av0 = ab0[it % PF], av1 = ab1[it % PF];
    if (it + PF < KITERS) {
      ab0[it % PF] = vld8(a0 + (it + PF) * 32);
      ab1[it % PF] = vld8(a1 + (it + PF) * 32);
    }
#pragma unroll
    for (int f = 0; f < NF; ++f) {
      v8bf b = *(const v8bf*)(bl + (4 * it + lc) * (NF * 128) + f * 128);
      acc[0][f] = mfma16(av0, b, acc[0][f]);
      acc[1][f] = mfma16(av1, b, acc[1][f]);
    }
  }
}

// ---------------- global-weight GEMM (init phases only) ----------------------
template <int KITERS, int NF>
__device__ inline void glb_gemm(const __bf16* act, const __bf16* wg,
                                int lane, f32x4 (&acc)[2][NF]) {
  const int ldk = KITERS * 32;
  const int lr = lane & 15, lc = lane >> 4;
  const __bf16* a0 = act + (size_t)lr * ldk + lc * 8;
  const __bf16* a1 = a0 + (size_t)16 * ldk;
  const __bf16* bp = wg + (size_t)lr * ldk + lc * 8;
#pragma unroll 8
  for (int it = 0; it < KITERS; ++it) {
    v8bf av0 = vld8(a0 + it * 32);
    v8bf av1 = vld8(a1 + it * 32);
#pragma unroll
    for (int f = 0; f < NF; ++f) {
      v8bf b = *(const v8bf*)(bp + (size_t)f * 16 * ldk + it * 32);
      acc[0][f] = mfma16(av0, b, acc[0][f]);
      acc[1][f] = mfma16(av1, b, acc[1][f]);
    }
  }
}

// ---------------- persistent kernel ------------------------------------------
__global__ __launch_bounds__(256, 1) void recurrent_kernel(
    const __bf16* __restrict__ wWi1, const __bf16* __restrict__ wWi2,
    const __bf16* __restrict__ wWt1s, const __bf16* __restrict__ wWt2,
    const __bf16* __restrict__ wWt3, const __bf16* __restrict__ wWt1x,
    const __bf16* __restrict__ x0bf, const float* __restrict__ past,
    __bf16* sbf, __bf16* z1, __bf16* z2,
    const float* __restrict__ bi1, const float* __restrict__ bi2,
    const float* __restrict__ bt1, const float* __restrict__ bt2,
    const float* __restrict__ bt3,
    float* out, unsigned* flags) {
  __shared__ alignas(16) __bf16 wl[32768];  // 64 KB weight slice
  const int w = blockIdx.x;
  const int tid = threadIdx.x, wid = tid >> 6, lane = tid & 63;
  const int cm = (lane >> 4) << 2, cn = lane & 15;
  const int m_w = wid * 32;  // wave's 32-row block of M=128
  unsigned* fA = flags;
  unsigned* fB = flags + 64;
  unsigned* fC = flags + 128;
  unsigned* fX = flags + 192;  // fX[t], t=1..511
  const __bf16* xc = (const __bf16*)out;  // aliases out (bf16 view, slice t)

  if (w < 64) {
    // ================= A role =================
    const int n0 = w * 32;
    stage_w<1024, 32>(wWt1s + (size_t)n0 * 1024, wl, tid);
    __syncthreads();
    for (int t = 1; t < 512; ++t) {
      wait_A(fC, fX + t, (unsigned)t);
      // hoist xc loads; latency hides under the gemm
      float xcv[2][2][4];
#pragma unroll
      for (int mf = 0; mf < 2; ++mf)
#pragma unroll
        for (int f = 0; f < 2; ++f)
#pragma unroll
          for (int r = 0; r < 4; ++r)
            xcv[mf][f][r] = vldbf(xc + ((size_t)(m_w + mf * 16 + cm + r) * 512 + t) * 2048 +
                                  (n0 + f * 16 + cn));
      f32x4 acc[2][2] = {};
      lds_gemm<32, 2, 16>(sbf + (size_t)m_w * 1024, 1024, wl, lane, acc);
#pragma unroll
      for (int mf = 0; mf < 2; ++mf)
#pragma unroll
        for (int f = 0; f < 2; ++f)
#pragma unroll
          for (int r = 0; r < 4; ++r) {
            int m = m_w + mf * 16 + cm + r, n = n0 + f * 16 + cn;
            vstbf(z1 + (size_t)m * 2048 + n, silu_f(acc[mf][f][r] + xcv[mf][f][r]));
          }
      flag_set(fA + w, (unsigned)t);
    }
  } else if (w < 128) {
    // ================= B role =================
    const int b = w - 64;
    const int n0 = b * 16;
    stage_w<2048, 16>(wWt2 + (size_t)n0 * 2048, wl, tid);
    __syncthreads();
    {  // init: h0 = silu(x0 @ Wi1^T + bi1) -> z2
      const float biasI = bi1[n0 + cn];
      f32x4 acc[2][1] = {};
      glb_gemm<32, 1>(x0bf + (size_t)m_w * 1024, wWi1 + (size_t)n0 * 1024, lane, acc);
#pragma unroll
      for (int mf = 0; mf < 2; ++mf)
#pragma unroll
        for (int r = 0; r < 4; ++r) {
          int m = m_w + mf * 16 + cm + r;
          vstbf(z2 + (size_t)m * 1024 + (n0 + cn), silu_f(acc[mf][0][r] + biasI));
        }
      flag_set(fB + b, 1u);
    }
    const float biasB = bt2[n0 + cn];
    for (int t = 1; t < 512; ++t) {
      flags_wait(fA, 64, (unsigned)t);
      f32x4 acc[2][1] = {};
      lds_gemm<64, 1, 16>(z1 + (size_t)m_w * 2048, 2048, wl, lane, acc);
#pragma unroll
      for (int mf = 0; mf < 2; ++mf)
#pragma unroll
        for (int r = 0; r < 4; ++r) {
          int m = m_w + mf * 16 + cm + r;
          vstbf(z2 + (size_t)m * 1024 + (n0 + cn), silu_f(acc[mf][0][r] + biasB));
        }
      flag_set(fB + b, (unsigned)(t + 1));
    }
  } else if (w < 160) {
    // ================= C role =================
    const int c = w - 128;
    const int n0 = c * 32;
    stage_w<1024, 32>(wWt3 + (size_t)n0 * 1024, wl, tid);
    __syncthreads();
    {  // init: s0 = h0 @ Wi2^T + bi2 -> out[:,0,:], sbf
      float bI[2] = {bi2[n0 + cn], bi2[n0 + 16 + cn]};
      flags_wait(fB, 64, 1u);
      f32x4 acc[2][2] = {};
      glb_gemm<32, 2>(z2 + (size_t)m_w * 1024, wWi2 + (size_t)n0 * 1024, lane, acc);
#pragma unroll
      for (int mf = 0; mf < 2; ++mf)
#pragma unroll
        for (int f = 0; f < 2; ++f)
#pragma unroll
          for (int r = 0; r < 4; ++r) {
            int m = m_w + mf * 16 + cm + r, n = n0 + f * 16 + cn;
            float v = acc[mf][f][r] + bI[f];
            out[(size_t)m * 524288 + n] = v;
            vstbf(sbf + (size_t)m * 1024 + n, v);
          }
      flag_set(fC + c, 1u);
    }
    const float bC[2] = {bt3[n0 + cn], bt3[n0 + 16 + cn]};
    for (int t = 1; t < 512; ++t) {
      flags_wait(fB, 64, (unsigned)(t + 1));
      f32x4 acc[2][2] = {};
      lds_gemm<32, 2, 16>(z2 + (size_t)m_w * 1024, 1024, wl, lane, acc);
#pragma unroll
      for (int mf = 0; mf < 2; ++mf)
#pragma unroll
        for (int f = 0; f < 2; ++f)
#pragma unroll
          for (int r = 0; r < 4; ++r) {
            int m = m_w + mf * 16 + cm + r, n = n0 + f * 16 + cn;
            float v = acc[mf][f][r] + bC[f];
            out[(size_t)m * 524288 + (size_t)t * 1024 + n] = v;
            vstbf(sbf + (size_t)m * 1024 + n, v);
          }
      flag_set(fC + c, (unsigned)(t + 1));
    }
  } else {
    // ================= X role: xc[t] = x_t @ Wt1x^T + bt1 =================
    const int x = w - 160;
    const int lr = lane & 15, lc = lane >> 4;
    for (int t = 1 + x; t < 512; t += 96) {
      const float* ap0 = past + ((size_t)(m_w + lr) * 512 + t) * 1024 + lc * 8;
      const float* ap1 = ap0 + (size_t)16 * 512 * 1024;
      __bf16* xcw = (__bf16*)out;
      for (int nc = 0; nc < 2048; nc += 64) {
        const __bf16* bp = wWt1x + (size_t)(nc + lr) * 1024 + lc * 8;
        f32x4 acc[2][4] = {};
#pragma unroll 8
        for (int it = 0; it < 32; ++it) {
          float4 a00 = *(const float4*)(ap0 + it * 32);
          float4 a01 = *(const float4*)(ap0 + it * 32 + 4);
          float4 a10 = *(const float4*)(ap1 + it * 32);
          float4 a11 = *(const float4*)(ap1 + it * 32 + 4);
          v8bf av0 = cvt8(a00, a01), av1 = cvt8(a10, a11);
#pragma unroll
          for (int f = 0; f < 4; ++f) {
            v8bf b = *(const v8bf*)(bp + (size_t)f * 16 * 1024 + it * 32);
            acc[0][f] = mfma16(av0, b, acc[0][f]);
            acc[1][f] = mfma16(av1, b, acc[1][f]);
          }
        }
#pragma unroll
        for (int mf = 0; mf < 2; ++mf)
#pragma unroll
          for (int f = 0; f < 4; ++f)
#pragma unroll
            for (int r = 0; r < 4; ++r) {
              int m = m_w + mf * 16 + cm + r, n = nc + f * 16 + cn;
              vstbf(xcw + ((size_t)m * 512 + t) * 2048 + n, acc[mf][f][r] + bt1[n]);
            }
      }
      flag_set(fX + t, 1u);
    }
  }
}

// ---------------- host launcher ----------------------------------------------
extern "C" void kernel_launch(void* const* d_in, const int* in_sizes, int n_in,
                              void* d_out, int out_size, void* d_ws, size_t ws_size,
                              hipStream_t stream) {
  (void)in_sizes; (void)n_in; (void)out_size; (void)ws_size;
  const float* past = (const float*)d_in[0];
  const float* Wi1 = (const float*)d_in[1];
  const float* bi1 = (const float*)d_in[2];
  const float* Wi2 = (const float*)d_in[3];
  const float* bi2 = (const float*)d_in[4];
  const float* Wt1 = (const float*)d_in[5];
  const float* bt1 = (const float*)d_in[6];
  const float* Wt2 = (const float*)d_in[7];
  const float* bt2 = (const float*)d_in[8];
  const float* Wt3 = (const float*)d_in[9];
  const float* bt3 = (const float*)d_in[10];
  float* out = (float*)d_out;

  char* ws = (char*)d_ws;
  size_t off = 0;
  unsigned* flags = (unsigned*)(ws + off); off += 4096;
  __bf16* wWi1 = (__bf16*)(ws + off);  off += (size_t)1024 * 1024 * 2;
  __bf16* wWi2 = (__bf16*)(ws + off);  off += (size_t)1024 * 1024 * 2;
  __bf16* wWt1s = (__bf16*)(ws + off); off += (size_t)2048 * 1024 * 2;
  __bf16* wWt1x = (__bf16*)(ws + off); off += (size_t)2048 * 1024 * 2;
  __bf16* wWt2 = (__bf16*)(ws + off);  off += (size_t)1024 * 2048 * 2;
  __bf16* wWt3 = (__bf16*)(ws + off);  off += (size_t)1024 * 1024 * 2;
  __bf16* x0bf = (__bf16*)(ws + off);  off += (size_t)128 * 1024 * 2;
  __bf16* sbf = (__bf16*)(ws + off);   off += (size_t)128 * 1024 * 2;
  __bf16* z1 = (__bf16*)(ws + off);    off += (size_t)128 * 2048 * 2;
  __bf16* z2 = (__bf16*)(ws + off);    off += (size_t)128 * 1024 * 2;

  hipMemsetAsync(flags, 0, 4096, stream);

  auto cvt = [&](const float* s, __bf16* d, int rows, int cols, int log2c,
                 int sstride, int soff) {
    int total8 = rows * cols / 8;
    hipLaunchKernelGGL(cvt_kernel, dim3((total8 + 255) / 256), dim3(256), 0,
                       stream, s, d, total8, log2c, sstride, soff);
  };
  cvt(Wi1, wWi1, 1024, 1024, 10, 1024, 0);
  cvt(Wi2, wWi2, 1024, 1024, 10, 1024, 0);
  cvt(Wt1, wWt1s, 2048, 1024, 10, 2048, 0);
  cvt(Wt1, wWt1x, 2048, 1024, 10, 2048, 1024);
  cvt(Wt2, wWt2, 1024, 2048, 11, 2048, 0);
  cvt(Wt3, wWt3, 1024, 1024, 10, 1024, 0);
  cvt(past, x0bf, 128, 1024, 10, 512 * 1024, 0);

  hipLaunchKernelGGL(recurrent_kernel, dim3(256), dim3(256), 0, stream,
                     wWi1, wWi2, wWt1s, wWt2, wWt3, wWt1x, x0bf, past,
                     sbf, z1, z2, bi1, bi2, bt1, bt2, bt3, out, flags);
}

// Round 4
// 22625.777 us; speedup vs baseline: 1.9687x; 1.9687x over previous
//
#include <hip/hip_runtime.h>
#include <hip/hip_bf16.h>

// TrueMarkovChain v4: phase-specialized persistent kernel, asm-coherence.
// Roles: A:32 WGs (z1 n-slice 64), B:32 (z2 n-slice 32), C:16 (s n-slice 64),
//        X:176 (xc hoist, 4-way n-split per t, t-stride 44).
// All cross-WG data via explicit `sc0 sc1` asm loads/stores (L3-coherent, no
// implicit per-load waits). Counted-vmcnt prefetch rings hide L3 latency.
// Weights LDS-resident per WG (128 KB).

typedef __bf16 v8bf __attribute__((ext_vector_type(8)));
typedef float f32x4 __attribute__((ext_vector_type(4)));

__device__ inline f32x4 mfma16(v8bf a, v8bf b, f32x4 c) {
  return __builtin_amdgcn_mfma_f32_16x16x32_bf16(a, b, c, 0, 0, 0);
}
__device__ inline float silu_f(float x) { return x / (1.f + __expf(-x)); }
__device__ inline v8bf as8(f32x4 x) { union { f32x4 f; v8bf b; } u; u.f = x; return u.b; }

__device__ inline v8bf cvt8(float4 a, float4 b) {
  v8bf v;
  v[0] = (__bf16)a.x; v[1] = (__bf16)a.y; v[2] = (__bf16)a.z; v[3] = (__bf16)a.w;
  v[4] = (__bf16)b.x; v[5] = (__bf16)b.y; v[6] = (__bf16)b.z; v[7] = (__bf16)b.w;
  return v;
}
__device__ inline unsigned short bfb(float v) {
  __bf16 b = (__bf16)v; unsigned short u; __builtin_memcpy(&u, &b, 2); return u;
}

// ---- coherent asm primitives (sc0 sc1 = L1/L2 bypass, L3 coherence point) ----
#define CLOAD16(dst, base, boff)                                        \
  asm volatile("global_load_dwordx4 %0, %1, off offset:%2 sc0 sc1"      \
               : "=v"(dst) : "v"(base), "n"(boff))

__device__ inline void cload_u16(unsigned& d, const __bf16* p) {
  asm volatile("global_load_ushort %0, %1, off sc0 sc1" : "=v"(d) : "v"(p));
}
__device__ inline void cstore16(__bf16* p, unsigned short u) {
  unsigned uu = u;
  asm volatile("global_store_short %0, %1, off sc0 sc1" :: "v"(p), "v"(uu) : "memory");
}
template <int N> __device__ inline void vwait() {
  asm volatile("s_waitcnt vmcnt(%0)" :: "n"(N) : "memory");
  __builtin_amdgcn_sched_barrier(0);
}
__device__ inline unsigned cpoll(const unsigned* p) {
  unsigned v;
  asm volatile("global_load_dword %0, %1, off sc0 sc1\n\ts_waitcnt vmcnt(0)"
               : "=v"(v) : "v"(p) : "memory");
  return v;
}
// release: all WG stores drained to L3, then single sc0sc1 flag store
__device__ inline void release_store(unsigned* f, unsigned v) {
  asm volatile("s_waitcnt vmcnt(0)" ::: "memory");
  __syncthreads();
  if (threadIdx.x == 0)
    asm volatile("global_store_dword %0, %1, off sc0 sc1" :: "v"(f), "v"(v) : "memory");
}

// ---------------- fp32 -> bf16 strided converter -----------------------------
__global__ void cvt_kernel(const float* __restrict__ src, __bf16* __restrict__ dst,
                           int total8, int log2cols, int sstride, int soff) {
  int i = blockIdx.x * 256 + threadIdx.x;
  if (i >= total8) return;
  long long e = (long long)i * 8;
  int r = (int)(e >> log2cols);
  int c = (int)(e & ((1LL << log2cols) - 1));
  const float* s = src + (size_t)r * sstride + soff + c;
  float4 f0 = *(const float4*)(s);
  float4 f1 = *(const float4*)(s + 4);
  *(v8bf*)(dst + e) = cvt8(f0, f1);
}

// ---------------- weight staging into LDS [K/8][NR][8] -----------------------
template <int K, int NR>
__device__ inline void stage_w(const __bf16* __restrict__ wg, __bf16* wl, int tid) {
  constexpr int TOT = (K / 8) * NR;
  for (int idx = tid; idx < TOT; idx += 256) {
    const int kb = idx / NR, n = idx % NR;
    *(v8bf*)(wl + (size_t)idx * 8) = *(const v8bf*)(wg + (size_t)n * K + kb * 8);
  }
}

// ---------------- counted-vmcnt ring GEMM (LDS weights, coherent act) --------
template <int KITERS, int NF, int DEPTH>
__device__ inline void ring_gemm(const __bf16* act, int ldk, const __bf16* wl,
                                 int lane, f32x4 (&acc)[2][NF]) {
  constexpr int CH = 8, NCH = KITERS / CH;
  constexpr int NR8 = NF * 128;
  const int lr = lane & 15, lc = lane >> 4;
  const __bf16* a0 = act + (size_t)lr * ldk + lc * 8;
  const __bf16* a1 = a0 + (size_t)16 * ldk;
  const __bf16* bl = wl + lr * 8;
  f32x4 r0[DEPTH][CH], r1[DEPTH][CH];
#pragma unroll
  for (int c = 0; c < (DEPTH < NCH ? DEPTH : NCH); ++c)
#pragma unroll
    for (int s = 0; s < CH; ++s) {
      CLOAD16(r0[c][s], a0, (c * CH + s) * 64);
      CLOAD16(r1[c][s], a1, (c * CH + s) * 64);
    }
#pragma unroll
  for (int c = 0; c < NCH; ++c) {
    const int wn = ((DEPTH - 1) < (NCH - 1 - c) ? (DEPTH - 1) : (NCH - 1 - c)) * 16;
    if (wn == 32) vwait<32>();
    else if (wn == 16) vwait<16>();
    else vwait<0>();
    const int buf = c % DEPTH;
#pragma unroll
    for (int s = 0; s < CH; ++s) {
      v8bf av0 = as8(r0[buf][s]), av1 = as8(r1[buf][s]);
      const int it = c * CH + s;
#pragma unroll
      for (int f = 0; f < NF; ++f) {
        v8bf b = *(const v8bf*)(bl + (size_t)(4 * it + lc) * NR8 + f * 128);
        acc[0][f] = mfma16(av0, b, acc[0][f]);
        acc[1][f] = mfma16(av1, b, acc[1][f]);
      }
    }
    if (c + DEPTH < NCH) {
#pragma unroll
      for (int s = 0; s < CH; ++s) {
        CLOAD16(r0[buf][s], a0, ((c + DEPTH) * CH + s) * 64);
        CLOAD16(r1[buf][s], a1, ((c + DEPTH) * CH + s) * 64);
      }
    }
  }
}

// ---------------- plain-load GEMM (init only; inputs host/first-touch fresh) -
template <int KITERS, int NF>
__device__ inline void glb_gemm(const __bf16* act, const __bf16* wg,
                                int lane, f32x4 (&acc)[2][NF]) {
  const int ldk = KITERS * 32;
  const int lr = lane & 15, lc = lane >> 4;
  const __bf16* a0 = act + (size_t)lr * ldk + lc * 8;
  const __bf16* a1 = a0 + (size_t)16 * ldk;
  const __bf16* bp = wg + (size_t)lr * ldk + lc * 8;
#pragma unroll 8
  for (int it = 0; it < KITERS; ++it) {
    v8bf av0 = *(const v8bf*)(a0 + it * 32);
    v8bf av1 = *(const v8bf*)(a1 + it * 32);
#pragma unroll
    for (int f = 0; f < NF; ++f) {
      v8bf b = *(const v8bf*)(bp + (size_t)f * 16 * ldk + it * 32);
      acc[0][f] = mfma16(av0, b, acc[0][f]);
      acc[1][f] = mfma16(av1, b, acc[1][f]);
    }
  }
}

// ---------------- persistent kernel ------------------------------------------
__global__ __launch_bounds__(256, 1) void recurrent_kernel(
    const __bf16* __restrict__ wWi1, const __bf16* __restrict__ wWi2,
    const __bf16* __restrict__ wWt1s, const __bf16* __restrict__ wWt2,
    const __bf16* __restrict__ wWt3, const __bf16* __restrict__ wWt1x,
    const __bf16* __restrict__ x0bf, const float* __restrict__ past,
    __bf16* sbf, __bf16* z1, __bf16* z2,
    const float* __restrict__ bi1, const float* __restrict__ bi2,
    const float* __restrict__ bt1, const float* __restrict__ bt2,
    const float* __restrict__ bt3,
    float* out, unsigned* flags) {
  __shared__ alignas(16) __bf16 wl[65536];  // 128 KB weight slice
  const int w = blockIdx.x;
  const int tid = threadIdx.x, wid = tid >> 6, lane = tid & 63;
  const int cm = (lane >> 4) << 2, cn = lane & 15;
  const int m_w = wid * 32;
  unsigned* fA = flags;          // 32
  unsigned* fB = flags + 64;     // 32
  unsigned* fC = flags + 128;    // 16
  unsigned* fX = flags + 192;    // [4][512]
  const __bf16* xc = (const __bf16*)out;

  if (w < 32) {
    // ================= A role: z1 = silu(s_prev @ Wt1s^T + xc[t]) ==========
    const int n0 = w * 64;
    stage_w<1024, 64>(wWt1s + (size_t)n0 * 1024, wl, tid);
    __syncthreads();
    for (int t = 1; t < 512; ++t) {
      // wait fC[0..15] >= t  AND  fX[nsl][t] >= 1 (nsl = (lane-16)&3)
      if (tid < 64) {
        const unsigned* p = (tid < 16) ? (fC + tid) : (fX + (size_t)((tid - 16) & 3) * 512 + t);
        const unsigned tgt = (tid < 16) ? (unsigned)t : 1u;
        while (cpoll(p) < tgt) __builtin_amdgcn_s_sleep(1);
      }
      __syncthreads();
      // issue xc loads first (oldest in vmcnt order; retire before ring waits)
      unsigned xcu[2][4][4];
#pragma unroll
      for (int mf = 0; mf < 2; ++mf)
#pragma unroll
        for (int f = 0; f < 4; ++f)
#pragma unroll
          for (int r = 0; r < 4; ++r)
            cload_u16(xcu[mf][f][r],
                      xc + ((size_t)(m_w + mf * 16 + cm + r) * 512 + t) * 2048 +
                          (n0 + f * 16 + cn));
      f32x4 acc[2][4] = {};
      ring_gemm<32, 4, 2>(sbf + (size_t)m_w * 1024, 1024, wl, lane, acc);
#pragma unroll
      for (int mf = 0; mf < 2; ++mf)
#pragma unroll
        for (int f = 0; f < 4; ++f)
#pragma unroll
          for (int r = 0; r < 4; ++r) {
            int m = m_w + mf * 16 + cm + r, n = n0 + f * 16 + cn;
            float xv = __uint_as_float(xcu[mf][f][r] << 16);
            cstore16(z1 + (size_t)m * 2048 + n, bfb(silu_f(acc[mf][f][r] + xv)));
          }
      release_store(fA + w, (unsigned)t);
    }
  } else if (w < 64) {
    // ================= B role: z2 = silu(z1 @ Wt2^T + bt2) =================
    const int b = w - 32;
    const int n0 = b * 32;
    stage_w<2048, 32>(wWt2 + (size_t)n0 * 2048, wl, tid);
    __syncthreads();
    const float biasB[2] = {bt2[n0 + cn], bt2[n0 + 16 + cn]};
    {  // init: h0 = silu(x0 @ Wi1^T + bi1) -> z2   (plain loads: host data)
      const float bI[2] = {bi1[n0 + cn], bi1[n0 + 16 + cn]};
      f32x4 acc[2][2] = {};
      glb_gemm<32, 2>(x0bf + (size_t)m_w * 1024, wWi1 + (size_t)n0 * 1024, lane, acc);
#pragma unroll
      for (int mf = 0; mf < 2; ++mf)
#pragma unroll
        for (int f = 0; f < 2; ++f)
#pragma unroll
          for (int r = 0; r < 4; ++r) {
            int m = m_w + mf * 16 + cm + r;
            cstore16(z2 + (size_t)m * 1024 + (n0 + f * 16 + cn),
                     bfb(silu_f(acc[mf][f][r] + bI[f])));
          }
      release_store(fB + b, 1u);
    }
    for (int t = 1; t < 512; ++t) {
      if (tid < 64) {
        const unsigned* p = fA + (tid & 31);
        while (cpoll(p) < (unsigned)t) __builtin_amdgcn_s_sleep(1);
      }
      __syncthreads();
      f32x4 acc[2][2] = {};
      ring_gemm<64, 2, 3>(z1 + (size_t)m_w * 2048, 2048, wl, lane, acc);
#pragma unroll
      for (int mf = 0; mf < 2; ++mf)
#pragma unroll
        for (int f = 0; f < 2; ++f)
#pragma unroll
          for (int r = 0; r < 4; ++r) {
            int m = m_w + mf * 16 + cm + r;
            cstore16(z2 + (size_t)m * 1024 + (n0 + f * 16 + cn),
                     bfb(silu_f(acc[mf][f][r] + biasB[f])));
          }
      release_store(fB + b, (unsigned)(t + 1));
    }
  } else if (w < 80) {
    // ================= C role: s = z2 @ Wt3^T + bt3 -> out, sbf ============
    const int c = w - 64;
    const int n0 = c * 64;
    stage_w<1024, 64>(wWt3 + (size_t)n0 * 1024, wl, tid);
    __syncthreads();
    float bC[4];
#pragma unroll
    for (int f = 0; f < 4; ++f) bC[f] = bt3[n0 + f * 16 + cn];
    {  // init: s0 = h0 @ Wi2^T + bi2 (z2 first-touch -> plain loads fresh)
      float bI[4];
#pragma unroll
      for (int f = 0; f < 4; ++f) bI[f] = bi2[n0 + f * 16 + cn];
      if (tid < 64) {
        const unsigned* p = fB + (tid & 31);
        while (cpoll(p) < 1u) __builtin_amdgcn_s_sleep(1);
      }
      __syncthreads();
      f32x4 acc[2][4] = {};
      glb_gemm<32, 4>(z2 + (size_t)m_w * 1024, wWi2 + (size_t)n0 * 1024, lane, acc);
#pragma unroll
      for (int mf = 0; mf < 2; ++mf)
#pragma unroll
        for (int f = 0; f < 4; ++f)
#pragma unroll
          for (int r = 0; r < 4; ++r) {
            int m = m_w + mf * 16 + cm + r, n = n0 + f * 16 + cn;
            float v = acc[mf][f][r] + bI[f];
            out[(size_t)m * 524288 + n] = v;
            cstore16(sbf + (size_t)m * 1024 + n, bfb(v));
          }
      release_store(fC + c, 1u);
    }
    for (int t = 1; t < 512; ++t) {
      if (tid < 64) {
        const unsigned* p = fB + (tid & 31);
        while (cpoll(p) < (unsigned)(t + 1)) __builtin_amdgcn_s_sleep(1);
      }
      __syncthreads();
      f32x4 acc[2][4] = {};
      ring_gemm<32, 4, 2>(z2 + (size_t)m_w * 1024, 1024, wl, lane, acc);
#pragma unroll
      for (int mf = 0; mf < 2; ++mf)
#pragma unroll
        for (int f = 0; f < 4; ++f)
#pragma unroll
          for (int r = 0; r < 4; ++r) {
            int m = m_w + mf * 16 + cm + r, n = n0 + f * 16 + cn;
            float v = acc[mf][f][r] + bC[f];
            out[(size_t)m * 524288 + (size_t)t * 1024 + n] = v;
            cstore16(sbf + (size_t)m * 1024 + n, bfb(v));
          }
      release_store(fC + c, (unsigned)(t + 1));
    }
  } else {
    // ================= X role: xc[t] = x_t @ Wt1x^T + bt1 ==================
    const int x = w - 80;           // 0..175
    const int tgrp = x >> 2;        // 0..43
    const int nsl = x & 3;          // n-slice of 512 cols
    const int lr = lane & 15, lc = lane >> 4;
    __bf16* xcw = (__bf16*)out;
    for (int t = 1 + tgrp; t < 512; t += 44) {
      const float* ap0 = past + ((size_t)(m_w + lr) * 512 + t) * 1024 + lc * 8;
      const float* ap1 = ap0 + (size_t)16 * 512 * 1024;
      for (int nc = nsl * 512; nc < nsl * 512 + 512; nc += 64) {
        const __bf16* bp = wWt1x + (size_t)(nc + lr) * 1024 + lc * 8;
        f32x4 acc[2][4] = {};
#pragma unroll 8
        for (int it = 0; it < 32; ++it) {
          float4 a00 = *(const float4*)(ap0 + it * 32);
          float4 a01 = *(const float4*)(ap0 + it * 32 + 4);
          float4 a10 = *(const float4*)(ap1 + it * 32);
          float4 a11 = *(const float4*)(ap1 + it * 32 + 4);
          v8bf av0 = cvt8(a00, a01), av1 = cvt8(a10, a11);
#pragma unroll
          for (int f = 0; f < 4; ++f) {
            v8bf b = *(const v8bf*)(bp + (size_t)f * 16 * 1024 + it * 32);
            acc[0][f] = mfma16(av0, b, acc[0][f]);
            acc[1][f] = mfma16(av1, b, acc[1][f]);
          }
        }
#pragma unroll
        for (int mf = 0; mf < 2; ++mf)
#pragma unroll
          for (int f = 0; f < 4; ++f)
#pragma unroll
            for (int r = 0; r < 4; ++r) {
              int m = m_w + mf * 16 + cm + r, n = nc + f * 16 + cn;
              cstore16(xcw + ((size_t)m * 512 + t) * 2048 + n,
                       bfb(acc[mf][f][r] + bt1[n]));
            }
      }
      release_store(fX + (size_t)nsl * 512 + t, 1u);
    }
  }
}

// ---------------- host launcher ----------------------------------------------
extern "C" void kernel_launch(void* const* d_in, const int* in_sizes, int n_in,
                              void* d_out, int out_size, void* d_ws, size_t ws_size,
                              hipStream_t stream) {
  (void)in_sizes; (void)n_in; (void)out_size; (void)ws_size;
  const float* past = (const float*)d_in[0];
  const float* Wi1 = (const float*)d_in[1];
  const float* bi1 = (const float*)d_in[2];
  const float* Wi2 = (const float*)d_in[3];
  const float* bi2 = (const float*)d_in[4];
  const float* Wt1 = (const float*)d_in[5];
  const float* bt1 = (const float*)d_in[6];
  const float* Wt2 = (const float*)d_in[7];
  const float* bt2 = (const float*)d_in[8];
  const float* Wt3 = (const float*)d_in[9];
  const float* bt3 = (const float*)d_in[10];
  float* out = (float*)d_out;

  char* ws = (char*)d_ws;
  size_t off = 0;
  unsigned* flags = (unsigned*)(ws + off); off += 16384;
  __bf16* wWi1 = (__bf16*)(ws + off);  off += (size_t)1024 * 1024 * 2;
  __bf16* wWi2 = (__bf16*)(ws + off);  off += (size_t)1024 * 1024 * 2;
  __bf16* wWt1s = (__bf16*)(ws + off); off += (size_t)2048 * 1024 * 2;
  __bf16* wWt1x = (__bf16*)(ws + off); off += (size_t)2048 * 1024 * 2;
  __bf16* wWt2 = (__bf16*)(ws + off);  off += (size_t)1024 * 2048 * 2;
  __bf16* wWt3 = (__bf16*)(ws + off);  off += (size_t)1024 * 1024 * 2;
  __bf16* x0bf = (__bf16*)(ws + off);  off += (size_t)128 * 1024 * 2;
  __bf16* sbf = (__bf16*)(ws + off);   off += (size_t)128 * 1024 * 2;
  __bf16* z1 = (__bf16*)(ws + off);    off += (size_t)128 * 2048 * 2;
  __bf16* z2 = (__bf16*)(ws + off);    off += (size_t)128 * 1024 * 2;

  hipMemsetAsync(flags, 0, 16384, stream);

  auto cvt = [&](const float* s, __bf16* d, int rows, int cols, int log2c,
                 int sstride, int soff) {
    int total8 = rows * cols / 8;
    hipLaunchKernelGGL(cvt_kernel, dim3((total8 + 255) / 256), dim3(256), 0,
                       stream, s, d, total8, log2c, sstride, soff);
  };
  cvt(Wi1, wWi1, 1024, 1024, 10, 1024, 0);
  cvt(Wi2, wWi2, 1024, 1024, 10, 1024, 0);
  cvt(Wt1, wWt1s, 2048, 1024, 10, 2048, 0);
  cvt(Wt1, wWt1x, 2048, 1024, 10, 2048, 1024);
  cvt(Wt2, wWt2, 1024, 2048, 11, 2048, 0);
  cvt(Wt3, wWt3, 1024, 1024, 10, 1024, 0);
  cvt(past, x0bf, 128, 1024, 10, 512 * 1024, 0);

  hipLaunchKernelGGL(recurrent_kernel, dim3(256), dim3(256), 0, stream,
                     wWi1, wWi2, wWt1s, wWt2, wWt3, wWt1x, x0bf, past,
                     sbf, z1, z2, bi1, bi2, bt1, bt2, bt3, out, flags);
}

// Round 6
// 10943.549 us; speedup vs baseline: 4.0703x; 2.0675x over previous
//
#include <hip/hip_runtime.h>
#include <hip/hip_bf16.h>

// TrueMarkovChain v6: 8 static groups x 32 WGs (group = bid&7, slot = bid>>3),
// 16 batch rows per group. Per step: A (z1, 64 cols/WG) -> B (z2, 32 cols/WG,
// k-split waves) -> C (s/out, 32 cols/WG, k-split). Acts staged to LDS by all
// 256 threads (parallel sc0sc1 burst); weights via per-wave plain rings
// (Wt3 first half LDS-pinned). All cross-WG data sc0sc1 (placement-safe).
// Guarded polls (no infinite spin). LDS ~100KB -> 1 WG/CU, 256 WGs co-resident.

typedef __bf16 v8bf __attribute__((ext_vector_type(8)));
typedef float f32x4 __attribute__((ext_vector_type(4)));
typedef unsigned u32x4 __attribute__((ext_vector_type(4)));

__device__ inline f32x4 mfma16(v8bf a, v8bf b, f32x4 c) {
  return __builtin_amdgcn_mfma_f32_16x16x32_bf16(a, b, c, 0, 0, 0);
}
__device__ inline float silu_f(float x) { return x / (1.f + __expf(-x)); }
__device__ inline v8bf as8(f32x4 x) { union { f32x4 f; v8bf b; } u; u.f = x; return u.b; }
__device__ inline v8bf cvt8(float4 a, float4 b) {
  v8bf v;
  v[0] = (__bf16)a.x; v[1] = (__bf16)a.y; v[2] = (__bf16)a.z; v[3] = (__bf16)a.w;
  v[4] = (__bf16)b.x; v[5] = (__bf16)b.y; v[6] = (__bf16)b.z; v[7] = (__bf16)b.w;
  return v;
}
__device__ inline unsigned bfb(float v) {
  __bf16 b = (__bf16)v; unsigned short u; __builtin_memcpy(&u, &b, 2); return (unsigned)u;
}

// sc0 sc1 = coherent at L3 (cross-WG safe). plain = L1/L2 cached (weights).
#define CLOADC(dst, base, boff)                                        \
  asm volatile("global_load_dwordx4 %0, %1, off offset:%2 sc0 sc1"     \
               : "=v"(dst) : "v"(base), "n"(boff))
#define CLOADP(dst, base, boff)                                        \
  asm volatile("global_load_dwordx4 %0, %1, off offset:%2"             \
               : "=v"(dst) : "v"(base), "n"(boff))

template <int N> __device__ inline void vwait() {
  asm volatile("s_waitcnt vmcnt(%0)" :: "n"(N) : "memory");
  __builtin_amdgcn_sched_barrier(0);
}
__device__ inline void vwait_n(int n) {
  switch (n) {
    case 0: vwait<0>(); break;   case 1: vwait<1>(); break;
    case 2: vwait<2>(); break;   case 3: vwait<3>(); break;
    case 4: vwait<4>(); break;   case 5: vwait<5>(); break;
    case 6: vwait<6>(); break;   case 7: vwait<7>(); break;
    case 8: vwait<8>(); break;   case 9: vwait<9>(); break;
    case 10: vwait<10>(); break; case 11: vwait<11>(); break;
    case 12: vwait<12>(); break; case 13: vwait<13>(); break;
    case 14: vwait<14>(); break; default: vwait<15>(); break;
  }
}

__device__ inline void st16c(__bf16* p, float v) {
  unsigned u = bfb(v);
  asm volatile("global_store_short %0, %1, off sc0 sc1" :: "v"(p), "v"(u) : "memory");
}
__device__ inline void st32c(float* p, float v) {
  asm volatile("global_store_dword %0, %1, off sc0 sc1" :: "v"(p), "v"(v) : "memory");
}

// Poll 32 contiguous flags (lanes 0..7, dwordx4 each) with backoff + guard.
__device__ inline void poll32(const unsigned* f, unsigned tgt) {
  if (threadIdx.x < 8) {
    const unsigned* p = f + threadIdx.x * 4;
    int guard = 0;
    while (true) {
      u32x4 v;
      asm volatile("global_load_dwordx4 %0, %1, off sc0 sc1\n\ts_waitcnt vmcnt(0)"
                   : "=v"(v) : "v"(p) : "memory");
      if (v[0] >= tgt && v[1] >= tgt && v[2] >= tgt && v[3] >= tgt) break;
      if (++guard > (1 << 20)) break;  // diagnostic escape: fail fast, not hang
      __builtin_amdgcn_s_sleep(2);
    }
  }
  __syncthreads();
}
// All WG stores drained to L3, then one flag store.
__device__ inline void release32(unsigned* f, int slot, unsigned v) {
  asm volatile("s_waitcnt vmcnt(0)" ::: "memory");
  __syncthreads();
  if (threadIdx.x == 0)
    asm volatile("global_store_dword %0, %1, off sc0 sc1" :: "v"(f + slot), "v"(v) : "memory");
}

// ---------------- fp32 -> bf16 strided converter -----------------------------
__global__ void cvt_kernel(const float* __restrict__ src, __bf16* __restrict__ dst,
                           int total8, int log2cols, int sstride, int soff) {
  int i = blockIdx.x * 256 + threadIdx.x;
  if (i >= total8) return;
  long long e = (long long)i * 8;
  int r = (int)(e >> log2cols);
  int c = (int)(e & ((1LL << log2cols) - 1));
  const float* s = src + (size_t)r * sstride + soff + c;
  float4 f0 = *(const float4*)(s);
  float4 f1 = *(const float4*)(s + 4);
  *(v8bf*)(dst + e) = cvt8(f0, f1);
}

// ---------------- xc[b][t] = x_t @ Wt1x^T + bt1 (v1-proven) ------------------
__global__ __launch_bounds__(512, 1) void xc_gemm_kernel(
    const float* __restrict__ past, const __bf16* __restrict__ w1x,
    const float* __restrict__ bt1, __bf16* __restrict__ xc) {
  const int t = blockIdx.y + 1;
  const int nb = blockIdx.x;
  const int tid = threadIdx.x, wid = tid >> 6, lane = tid & 63;
  const int wm = wid >> 1, wn = wid & 1;
  const int m0 = wm * 32;
  const int n0 = nb * 512 + wn * 256;
  const int lr = lane & 15, lc = lane >> 4;
  f32x4 acc[2][16] = {};
  const float* a0p = past + ((size_t)(m0 + lr) * 512 + t) * 1024 + lc * 8;
  const float* a1p = a0p + (size_t)16 * 512 * 1024;
  const __bf16* bp = w1x + (size_t)(n0 + lr) * 1024 + lc * 8;
  for (int k = 0; k < 1024; k += 32) {
    float4 x00 = *(const float4*)(a0p + k);
    float4 x01 = *(const float4*)(a0p + k + 4);
    float4 x10 = *(const float4*)(a1p + k);
    float4 x11 = *(const float4*)(a1p + k + 4);
    v8bf a0 = cvt8(x00, x01), a1 = cvt8(x10, x11);
#pragma unroll
    for (int j = 0; j < 16; ++j) {
      v8bf b = *(const v8bf*)(bp + (size_t)j * 16 * 1024 + k);
      acc[0][j] = mfma16(a0, b, acc[0][j]);
      acc[1][j] = mfma16(a1, b, acc[1][j]);
    }
  }
  const int cm = (lane >> 4) << 2, cn = lane & 15;
#pragma unroll
  for (int f = 0; f < 2; ++f)
#pragma unroll
    for (int j = 0; j < 16; ++j) {
      int n = n0 + j * 16 + cn;
      float bias = bt1[n];
#pragma unroll
      for (int r = 0; r < 4; ++r) {
        int m = m0 + f * 16 + cm + r;
        xc[((size_t)m * 512 + t) * 2048 + n] = (__bf16)(acc[f][j][r] + bias);
      }
    }
}

// ---- stage a [16][K] bf16 act tile from global (sc0sc1) into swizzled LDS ---
template <int K>
__device__ inline void stage_act(char* lds, const __bf16* src, int tid) {
  constexpr int CH = K / 128;           // chunks of 8 elems per thread
  constexpr int SH = (K == 2048) ? 8 : 7;
  f32x4 v[CH];
#pragma unroll
  for (int i = 0; i < CH; ++i) {
    int idx = tid + i * 256;
    int row = idx >> SH, kc = idx & ((K / 8) - 1);
    CLOADC(v[i], src + (size_t)row * K + kc * 8, 0);
  }
  vwait<0>();
#pragma unroll
  for (int i = 0; i < CH; ++i) {
    int idx = tid + i * 256;
    int row = idx >> SH, kc = idx & ((K / 8) - 1);
    unsigned byte = ((unsigned)(row * K + kc * 8) * 2) ^ ((unsigned)(row & 7) << 4);
    *(f32x4*)(lds + byte) = v[i];
  }
  __syncthreads();
}

// ---- GEMM: LDS act (swizzled) + global weight ring (plain, PFD-deep) --------
template <int KIT, int PFD, int KS>
__device__ inline f32x4 gemm_aw(const char* ldsa, int k0,
                                const __bf16* wtb, int lane) {
  const int lr = lane & 15, lc = lane >> 4;
  f32x4 acc = {0.f, 0.f, 0.f, 0.f};
  f32x4 rw[PFD];
#pragma unroll
  for (int j = 0; j < PFD; ++j) CLOADP(rw[j], wtb, j * 64);
#pragma unroll
  for (int it = 0; it < KIT; ++it) {
    vwait_n((KIT - 1 - it) < (PFD - 1) ? (KIT - 1 - it) : (PFD - 1));
    v8bf b = as8(rw[it % PFD]);
    if (it + PFD < KIT) CLOADP(rw[it % PFD], wtb, (it + PFD) * 64);
    int k = k0 + it * 32 + lc * 8;
    unsigned byte = ((unsigned)(lr * KS + k) * 2) ^ ((unsigned)(lr & 7) << 4);
    v8bf a = *(const v8bf*)(ldsa + byte);
    acc = mfma16(a, b, acc);
  }
  return acc;
}

// ---- GEMM: LDS act + LDS weights ([kb][32][8] layout) -----------------------
template <int KIT, int KS>
__device__ inline f32x4 gemm_aa(const char* ldsa, int k0,
                                const char* ldsw, int col, int lane) {
  const int lr = lane & 15, lc = lane >> 4;
  f32x4 acc = {0.f, 0.f, 0.f, 0.f};
#pragma unroll
  for (int it = 0; it < KIT; ++it) {
    int k = k0 + it * 32 + lc * 8;
    unsigned abyte = ((unsigned)(lr * KS + k) * 2) ^ ((unsigned)(lr & 7) << 4);
    v8bf a = *(const v8bf*)(ldsa + abyte);
    v8bf b = *(const v8bf*)(ldsw + (size_t)((it * 4 + lc) * 32 + col) * 16);
    acc = mfma16(a, b, acc);
  }
  return acc;
}

// ---------------- persistent recurrence --------------------------------------
__global__ __launch_bounds__(256, 1) void recurrent_kernel(
    const __bf16* __restrict__ wWi1, const __bf16* __restrict__ wWi2,
    const __bf16* __restrict__ wWt1s, const __bf16* __restrict__ wWt2,
    const __bf16* __restrict__ wWt3, const __bf16* __restrict__ x0bf,
    __bf16* __restrict__ sbf, __bf16* __restrict__ z1, __bf16* __restrict__ z2,
    const float* __restrict__ bi1, const float* __restrict__ bi2,
    const float* __restrict__ bt2, const float* __restrict__ bt3,
    float* __restrict__ out, unsigned* __restrict__ flags) {
  __shared__ alignas(16) char actbuf[65536];   // [16][K<=2048] swizzled acts
  __shared__ alignas(16) char wt3buf[32768];   // Wt3 slice, K 0..512
  __shared__ float red[512];                   // k-split reduce
  const int bid = blockIdx.x;
  const int g = bid & 7, s = bid >> 3;
  const int tid = threadIdx.x, wid = tid >> 6, lane = tid & 63;
  const int lr = lane & 15, lc = lane >> 4;
  const int cm = lc << 2, cn = lr;
  const int wn = wid & 1, wk = wid >> 1;
  const int b0 = g * 16;
  unsigned* fA = flags + g * 96;
  unsigned* fB = fA + 32;
  unsigned* fC = fA + 64;
  __bf16* sbf_g = sbf + (size_t)g * 16 * 1024;
  __bf16* z1_g = z1 + (size_t)g * 16 * 2048;
  __bf16* z2_g = z2 + (size_t)g * 16 * 1024;
  const __bf16* xc = (const __bf16*)out;

  // stage Wt3 slice (cols s*32..+32, K<512) -> wt3buf [kb=64][32][8]
  {
    const __bf16* wg = wWt3 + (size_t)s * 32 * 1024;
    for (int idx = tid; idx < 2048; idx += 256) {
      int kb = idx >> 5, c = idx & 31;
      *(f32x4*)(wt3buf + (size_t)idx * 16) = *(const f32x4*)(wg + (size_t)c * 1024 + kb * 8);
    }
  }

  const int nBC = s * 32 + wn * 16 + cn;
  const int nA = s * 64 + wid * 16 + cn;
  const float bB = bt2[nBC], bC = bt3[nBC];
  const float bI1 = bi1[nBC], bI2 = bi2[nBC];

  // ---- init-B: h0 = silu(x0 @ Wi1^T + bi1) -> z2 ----
  stage_act<1024>(actbuf, x0bf + (size_t)b0 * 1024, tid);  // also syncs wt3buf
  {
    f32x4 acc = gemm_aw<16, 12, 1024>(
        actbuf, wk * 512, wWi1 + (size_t)(s * 32 + wn * 16 + lr) * 1024 + wk * 512 + lc * 8, lane);
    if (wk) {
#pragma unroll
      for (int r = 0; r < 4; ++r) red[wn * 256 + (cm + r) * 16 + cn] = acc[r];
    }
    __syncthreads();
    if (!wk) {
#pragma unroll
      for (int r = 0; r < 4; ++r) {
        float v = acc[r] + red[wn * 256 + (cm + r) * 16 + cn] + bI1;
        st16c(z2_g + (size_t)(cm + r) * 1024 + nBC, silu_f(v));
      }
    }
  }
  release32(fB, s, 1u);
  // ---- init-C: s0 = h0 @ Wi2^T + bi2 -> out[:,0,:], sbf ----
  poll32(fB, 1u);
  stage_act<1024>(actbuf, z2_g, tid);
  {
    f32x4 acc = gemm_aw<16, 12, 1024>(
        actbuf, wk * 512, wWi2 + (size_t)(s * 32 + wn * 16 + lr) * 1024 + wk * 512 + lc * 8, lane);
    if (wk) {
#pragma unroll
      for (int r = 0; r < 4; ++r) red[wn * 256 + (cm + r) * 16 + cn] = acc[r];
    }
    __syncthreads();
    if (!wk) {
#pragma unroll
      for (int r = 0; r < 4; ++r) {
        float v = acc[r] + red[wn * 256 + (cm + r) * 16 + cn] + bI2;
        st32c(out + (size_t)(b0 + cm + r) * 524288 + nBC, v);
        st16c(sbf_g + (size_t)(cm + r) * 1024 + nBC, v);
      }
    }
  }
  release32(fC, s, 1u);

  for (int t = 1; t < 512; ++t) {
    // ---- A: z1 = silu(s_prev @ Wt1s^T + xc[t]) ---- (4 waves x 16 cols, full K)
    poll32(fC, (unsigned)t);
    stage_act<1024>(actbuf, sbf_g, tid);
    {
      unsigned xcu[4];
#pragma unroll
      for (int r = 0; r < 4; ++r) {
        const __bf16* p = xc + ((size_t)(b0 + cm + r) * 512 + t) * 2048 + nA;
        asm volatile("global_load_ushort %0, %1, off sc0 sc1" : "=v"(xcu[r]) : "v"(p));
      }
      f32x4 acc = gemm_aw<32, 12, 1024>(
          actbuf, 0, wWt1s + (size_t)(s * 64 + wid * 16 + lr) * 1024 + lc * 8, lane);
      // gemm's final vmcnt(0) also retired xcu
#pragma unroll
      for (int r = 0; r < 4; ++r) {
        float xv = __uint_as_float(xcu[r] << 16);
        st16c(z1_g + (size_t)(cm + r) * 2048 + nA, silu_f(acc[r] + xv));
      }
    }
    release32(fA, s, (unsigned)t);
    // ---- B: z2 = silu(z1 @ Wt2^T + bt2) ---- (2 cols x 2 k-halves)
    poll32(fA, (unsigned)t);
    stage_act<2048>(actbuf, z1_g, tid);
    {
      f32x4 acc = gemm_aw<32, 12, 2048>(
          actbuf, wk * 1024,
          wWt2 + (size_t)(s * 32 + wn * 16 + lr) * 2048 + wk * 1024 + lc * 8, lane);
      if (wk) {
#pragma unroll
        for (int r = 0; r < 4; ++r) red[wn * 256 + (cm + r) * 16 + cn] = acc[r];
      }
      __syncthreads();
      if (!wk) {
#pragma unroll
        for (int r = 0; r < 4; ++r) {
          float v = acc[r] + red[wn * 256 + (cm + r) * 16 + cn] + bB;
          st16c(z2_g + (size_t)(cm + r) * 1024 + nBC, silu_f(v));
        }
      }
    }
    release32(fB, s, (unsigned)(t + 1));
    // ---- C: s = z2 @ Wt3^T + bt3 -> out, sbf ---- (2 cols x 2 k-halves)
    poll32(fB, (unsigned)(t + 1));
    stage_act<1024>(actbuf, z2_g, tid);
    {
      f32x4 acc;
      if (!wk)
        acc = gemm_aa<16, 1024>(actbuf, 0, wt3buf, wn * 16 + lr, lane);
      else
        acc = gemm_aw<16, 12, 1024>(
            actbuf, 512, wWt3 + (size_t)(s * 32 + wn * 16 + lr) * 1024 + 512 + lc * 8, lane);
      if (wk) {
#pragma unroll
        for (int r = 0; r < 4; ++r) red[wn * 256 + (cm + r) * 16 + cn] = acc[r];
      }
      __syncthreads();
      if (!wk) {
#pragma unroll
        for (int r = 0; r < 4; ++r) {
          float v = acc[r] + red[wn * 256 + (cm + r) * 16 + cn] + bC;
          st32c(out + (size_t)(b0 + cm + r) * 524288 + (size_t)t * 1024 + nBC, v);
          st16c(sbf_g + (size_t)(cm + r) * 1024 + nBC, v);
        }
      }
    }
    release32(fC, s, (unsigned)(t + 1));
  }
}

// ---------------- host launcher ----------------------------------------------
extern "C" void kernel_launch(void* const* d_in, const int* in_sizes, int n_in,
                              void* d_out, int out_size, void* d_ws, size_t ws_size,
                              hipStream_t stream) {
  (void)in_sizes; (void)n_in; (void)out_size; (void)ws_size;
  const float* past = (const float*)d_in[0];
  const float* Wi1 = (const float*)d_in[1];
  const float* bi1 = (const float*)d_in[2];
  const float* Wi2 = (const float*)d_in[3];
  const float* bi2 = (const float*)d_in[4];
  const float* Wt1 = (const float*)d_in[5];
  const float* bt1 = (const float*)d_in[6];
  const float* Wt2 = (const float*)d_in[7];
  const float* bt2 = (const float*)d_in[8];
  const float* Wt3 = (const float*)d_in[9];
  const float* bt3 = (const float*)d_in[10];
  float* out = (float*)d_out;

  char* ws = (char*)d_ws;
  size_t off = 0;
  unsigned* flags = (unsigned*)(ws + off); off += 4096;
  __bf16* wWi1 = (__bf16*)(ws + off);  off += (size_t)1024 * 1024 * 2;
  __bf16* wWi2 = (__bf16*)(ws + off);  off += (size_t)1024 * 1024 * 2;
  __bf16* wWt1s = (__bf16*)(ws + off); off += (size_t)2048 * 1024 * 2;
  __bf16* wWt1x = (__bf16*)(ws + off); off += (size_t)2048 * 1024 * 2;
  __bf16* wWt2 = (__bf16*)(ws + off);  off += (size_t)1024 * 2048 * 2;
  __bf16* wWt3 = (__bf16*)(ws + off);  off += (size_t)1024 * 1024 * 2;
  __bf16* x0bf = (__bf16*)(ws + off);  off += (size_t)128 * 1024 * 2;
  __bf16* sbf = (__bf16*)(ws + off);   off += (size_t)8 * 16 * 1024 * 2;
  __bf16* z1 = (__bf16*)(ws + off);    off += (size_t)8 * 16 * 2048 * 2;
  __bf16* z2 = (__bf16*)(ws + off);    off += (size_t)8 * 16 * 1024 * 2;

  hipMemsetAsync(flags, 0, 4096, stream);

  auto cvt = [&](const float* s, __bf16* d, int rows, int cols, int log2c,
                 int sstride, int soff) {
    int total8 = rows * cols / 8;
    cvt_kernel<<<dim3((total8 + 255) / 256), dim3(256), 0, stream>>>(
        s, d, total8, log2c, sstride, soff);
  };
  cvt(Wi1, wWi1, 1024, 1024, 10, 1024, 0);
  cvt(Wi2, wWi2, 1024, 1024, 10, 1024, 0);
  cvt(Wt1, wWt1s, 2048, 1024, 10, 2048, 0);
  cvt(Wt1, wWt1x, 2048, 1024, 10, 2048, 1024);
  cvt(Wt2, wWt2, 1024, 2048, 11, 2048, 0);
  cvt(Wt3, wWt3, 1024, 1024, 10, 1024, 0);
  cvt(past, x0bf, 128, 1024, 10, 512 * 1024, 0);

  xc_gemm_kernel<<<dim3(4, 511), dim3(512), 0, stream>>>(
      past, wWt1x, bt1, (__bf16*)d_out);

  recurrent_kernel<<<dim3(256), dim3(256), 0, stream>>>(
      wWi1, wWi2, wWt1s, wWt2, wWt3, x0bf, sbf, z1, z2,
      bi1, bi2, bt2, bt3, out, flags);
}